// Round 7
// baseline (2172.048 us; speedup 1.0000x reference)
//
#include <hip/hip_runtime.h>
#include <hip/hip_bf16.h>

constexpr int NB = 16;      // batch
constexpr int NN = 1024;    // nodes
constexpr int DI = 256;     // in dim
constexpr int DOv = 256;    // out dim
constexpr float NEG = 0.2f;

#define GLOAD_LDS16(g, l) __builtin_amdgcn_global_load_lds( \
    (const __attribute__((address_space(1))) unsigned int*)(g), \
    (__attribute__((address_space(3))) unsigned int*)(l), 16, 0, 0)

// ---------------- Kernel 1: Wh[m][o] = sum_k h[m][k] * W[o][k] ----------------
// BM=128, BO=64, BK=32, 512 thr, 4x4 outputs/thread. Double-buffered
// global_load_lds staging, one barrier per K-step, STAGE(next) before compute.
// LDS linear (gload_lds requirement); conflicts broken by XOR-swizzling BOTH
// the per-lane global source and the read index (rule #21).
__global__ __launch_bounds__(512, 4)
void gemm_wh(const float* __restrict__ h, const float* __restrict__ W,
             float* __restrict__ Wh) {
    __shared__ __align__(16) float4 Asl[2][1024];  // 2 x 16 KB  [m(128)][kc(8)] swizzled
    __shared__ __align__(16) float4 Bsl[2][512];   // 2 x  8 KB  [o(64)][kc(8)] swizzled
    const int t  = threadIdx.x;
    const int mb = blockIdx.x * 128;
    const int ob = blockIdx.y * 64;
    const int rg = t >> 4;          // 0..31
    const int cg = t & 15;          // 0..15
    const int m0 = rg * 4, o0 = cg * 4;
    float acc[4][4] = {};

    auto STAGE = [&](int buf, int k0) {
        #pragma unroll
        for (int r = 0; r < 2; ++r) {                 // A: 1024 slots, 2/thread
            int s = r * 512 + t;
            int m = s >> 3;
            int kg = (s & 7) ^ ((s >> 6) & 7);        // inverse swizzle on SOURCE
            GLOAD_LDS16(&h[(size_t)(mb + m) * DI + k0 + kg * 4], (float*)&Asl[buf][s]);
        }
        {                                             // B: 512 slots, 1/thread
            int s = t;
            int o = s >> 3;
            int kg = (s & 7) ^ ((s >> 5) & 7);
            GLOAD_LDS16(&W[(size_t)(ob + o) * DI + k0 + kg * 4], (float*)&Bsl[buf][s]);
        }
    };

    STAGE(0, 0);
    __syncthreads();                                  // prologue drain (once)
    for (int kb = 0; kb < 8; ++kb) {
        const int cur = kb & 1;
        if (kb < 7) STAGE(cur ^ 1, (kb + 1) * 32);    // async, hidden under compute
        #pragma unroll
        for (int kg = 0; kg < 8; ++kg) {
            float4 bf[4], af[4];
            #pragma unroll
            for (int c = 0; c < 4; ++c) {
                int o = o0 + c;
                bf[c] = Bsl[cur][o * 8 + (kg ^ ((o >> 2) & 7))];
            }
            #pragma unroll
            for (int i = 0; i < 4; ++i) {
                int m = m0 + i;
                af[i] = Asl[cur][m * 8 + (kg ^ ((m >> 3) & 7))];
            }
            #pragma unroll
            for (int i = 0; i < 4; ++i)
                #pragma unroll
                for (int c = 0; c < 4; ++c) {
                    acc[i][c] += af[i].x * bf[c].x;
                    acc[i][c] += af[i].y * bf[c].y;
                    acc[i][c] += af[i].z * bf[c].z;
                    acc[i][c] += af[i].w * bf[c].w;
                }
        }
        __syncthreads();      // stage for kb+1 landed; reads of cur done
    }
    #pragma unroll
    for (int i = 0; i < 4; ++i)
        *(float4*)&Wh[(size_t)(mb + m0 + i) * DOv + ob + o0] =
            make_float4(acc[i][0], acc[i][1], acc[i][2], acc[i][3]);
}

// ---------------- Kernel 2: ei = Wh . a1 ; ej = Wh . a2 (per row) ----------------
__global__ __launch_bounds__(256)
void ei_ej(const float* __restrict__ Wh, const float* __restrict__ a,
           float* __restrict__ ei, float* __restrict__ ej) {
    const int t = threadIdx.x;
    const int w = t >> 6, l = t & 63;
    const int row = blockIdx.x * 4 + w;
    float4 wv = *(const float4*)&Wh[(size_t)row * DOv + l * 4];
    float4 a1 = *(const float4*)&a[l * 4];
    float4 a2 = *(const float4*)&a[DOv + l * 4];
    float s1 = wv.x*a1.x + wv.y*a1.y + wv.z*a1.z + wv.w*a1.w;
    float s2 = wv.x*a2.x + wv.y*a2.y + wv.z*a2.z + wv.w*a2.w;
    #pragma unroll
    for (int off = 32; off; off >>= 1) {
        s1 += __shfl_xor(s1, off);
        s2 += __shfl_xor(s2, off);
    }
    if (l == 0) { ei[row] = s1; ej[row] = s2; }
}

// ---------------- Kernel 3: fused masked-softmax attention + PV ----------------
// 32 i-rows, 512 thr. whs (gload_lds, 2x32KB) AND ps double-buffered ->
// ONE barrier per tile; STAGE(i+2) issued right after barrier(i) into the
// buffer PV(i) just released, drained by barrier(i+1) (a full EPHASE+PV in
// flight covers latency). PV is fully static: NO pointer casts on private
// data (scratch bug in r4/r6: float* cast of float4[4] -> 435 MB phantom
// writes). Softmax shift-invariance + |e|<=~8 -> no max pass; l==0 -> out 0.
constexpr int RI = 32;   // rows per block
constexpr int TJ = 32;   // j-tile
__global__ __launch_bounds__(512, 4)
void gat_attn(const float* __restrict__ Wh, const float* __restrict__ ei,
              const float* __restrict__ ej, const int* __restrict__ adj,
              float* __restrict__ out) {
    __shared__ __align__(16) float whs[2][TJ * DOv];   // 64 KB, LINEAR (gload_lds dest)
    __shared__ __align__(16) float ps[2][RI][TJ + 4];  // 9.2 KB
    __shared__ float ejs[NN];                          // 4 KB
    __shared__ float ls[RI];
    // ~78 KB -> 2 blocks/CU

    const int t = threadIdx.x;
    // XCD-bijective swizzle: 512 blocks = 8 XCDs * 64 -> 2 batches per XCD L2.
    const int swz = (blockIdx.x & 7) * 64 + (blockIdx.x >> 3);
    const int b  = swz >> 5;
    const int ib = (swz & 31) * RI;

    *(float2*)&ejs[t * 2] = *(const float2*)&ej[(size_t)b * NN + t * 2];

    const int erow = t >> 4;        // e-phase: 1 row x 2 j per thread
    const int ej0  = (t & 15) * 2;
    const int rg = t >> 6;          // PV: wave 0..7
    const int m0 = rg * 4;          // wave-uniform -> ps reads broadcast
    const int o0 = (t & 63) * 4;    // ds_read_b128, conflict-free

    float acc[4][4] = {};
    float lsum = 0.f;

    const float* whsrc = Wh + (size_t)b * NN * DOv;
    const int*   arow  = adj + ((size_t)b * NN + ib + erow) * NN;
    const float  eiv   = ei[(size_t)b * NN + ib + erow];

    auto STAGE = [&](int buf, int tile) {
        const float* src = whsrc + (size_t)tile * TJ * DOv;
        float* dst = whs[buf];
        #pragma unroll
        for (int r = 0; r < 4; ++r) {
            int idx = r * 512 + t;               // float4-slot 0..2047
            GLOAD_LDS16(src + idx * 4, dst + idx * 4);
        }
    };
    auto EPHASE = [&](int tile, int buf, int2 am) {
        float2 ejv = *(const float2*)&ejs[tile * TJ + ej0];
        float e0 = eiv + ejv.x; e0 = e0 > 0.f ? e0 : NEG * e0;
        float e1 = eiv + ejv.y; e1 = e1 > 0.f ? e1 : NEG * e1;
        float p0 = am.x ? __expf(e0) : 0.f;
        float p1 = am.y ? __expf(e1) : 0.f;
        *(float2*)&ps[buf][erow][ej0] = make_float2(p0, p1);
        lsum += p0 + p1;
    };

    // ---- prologue ----
    STAGE(0, 0);
    STAGE(1, 1);
    int2 am0 = *(const int2*)&arow[ej0];
    int2 amc = *(const int2*)&arow[TJ + ej0];
    __syncthreads();                  // both stages drained; ejs visible
    EPHASE(0, 0, am0);
    __syncthreads();                  // ps[0] visible

#define FMA4(K, PV, W) \
    acc[K][0] += (PV) * (W).x; acc[K][1] += (PV) * (W).y; \
    acc[K][2] += (PV) * (W).z; acc[K][3] += (PV) * (W).w;
#define PVSTEP(U, MEM) { \
    float4 w4 = *(const float4*)&whc[(j2 + U) * DOv + o0]; \
    FMA4(0, pk0.MEM, w4) FMA4(1, pk1.MEM, w4) \
    FMA4(2, pk2.MEM, w4) FMA4(3, pk3.MEM, w4) }

    for (int i = 0; i < 32; ++i) {
        const int cur = i & 1;
        if (i + 1 < 32) {
            EPHASE(i + 1, cur ^ 1, amc);
            if (i + 2 < 32) amc = *(const int2*)&arow[(i + 2) * TJ + ej0];
        }
        const float* whc = whs[cur];
        #pragma unroll
        for (int j2 = 0; j2 < TJ; j2 += 4) {
            float4 pk0 = *(const float4*)&ps[cur][m0 + 0][j2];
            float4 pk1 = *(const float4*)&ps[cur][m0 + 1][j2];
            float4 pk2 = *(const float4*)&ps[cur][m0 + 2][j2];
            float4 pk3 = *(const float4*)&ps[cur][m0 + 3][j2];
            PVSTEP(0, x) PVSTEP(1, y) PVSTEP(2, z) PVSTEP(3, w)
        }
        __syncthreads();              // ps[cur^1] visible; stage(i+1->whs) drained
        if (i + 2 < 32) STAGE(cur, i + 2);   // PV(i) done with whs[cur]
    }
#undef PVSTEP
#undef FMA4

    #pragma unroll
    for (int off = 8; off; off >>= 1) lsum += __shfl_xor(lsum, off);
    if ((t & 15) == 0) ls[erow] = lsum;
    __syncthreads();

    #pragma unroll
    for (int k = 0; k < 4; ++k) {
        float lv = ls[m0 + k];
        float iv = lv > 0.f ? 1.0f / lv : 0.f;   // all-masked row -> 0
        *(float4*)&out[((size_t)b * NN + ib + m0 + k) * DOv + o0] =
            make_float4(acc[k][0]*iv, acc[k][1]*iv, acc[k][2]*iv, acc[k][3]*iv);
    }
}

// ---------------- launch ----------------
extern "C" void kernel_launch(void* const* d_in, const int* in_sizes, int n_in,
                              void* d_out, int out_size, void* d_ws, size_t ws_size,
                              hipStream_t stream) {
    const float* h   = (const float*)d_in[0];
    const int*   adj = (const int*)d_in[1];
    const float* W   = (const float*)d_in[2];
    const float* a   = (const float*)d_in[3];
    float* out = (float*)d_out;

    float* Wh = (float*)d_ws;                       // 16 MB
    float* ei = Wh + (size_t)NB * NN * DOv;
    float* ej = ei + (size_t)NB * NN;

    gemm_wh<<<dim3((NB * NN) / 128, DOv / 64), 512, 0, stream>>>(h, W, Wh);
    ei_ej<<<(NB * NN) / 4, 256, 0, stream>>>(Wh, a, ei, ej);
    gat_attn<<<NB * NN / RI, 512, 0, stream>>>(Wh, ei, ej, adj, out);
}

// Round 8
// 304.698 us; speedup vs baseline: 7.1285x; 7.1285x over previous
//
#include <hip/hip_runtime.h>
#include <hip/hip_bf16.h>

constexpr int NB = 16;      // batch
constexpr int NN = 1024;    // nodes
constexpr int DI = 256;     // in dim
constexpr int DOv = 256;    // out dim
constexpr float NEG = 0.2f;

#define GLOAD_LDS16(g, l) __builtin_amdgcn_global_load_lds( \
    (const __attribute__((address_space(1))) unsigned int*)(g), \
    (__attribute__((address_space(3))) unsigned int*)(l), 16, 0, 0)

// ---------------- Kernel 1: Wh[m][o] = sum_k h[m][k] * W[o][k] ----------------
// BM=128, BO=64, BK=32, 512 thr, 4x4 outputs/thread. Double-buffered
// global_load_lds staging, one barrier per K-step, STAGE(next) before compute
// (drain at end-of-iter barrier is covered by the 8x inner compute).
// LDS linear (gload_lds requirement); conflicts broken by XOR-swizzling BOTH
// the per-lane global source and the read index (rule #21).
// NO lambdas (scratch landmine r4/r6/r7): staging is a textual macro.
#define GEMM_STAGE(BUF, K0) { \
    _Pragma("unroll") \
    for (int _r = 0; _r < 2; ++_r) { \
        int _s = _r * 512 + t; \
        int _m = _s >> 3; \
        int _kg = (_s & 7) ^ ((_s >> 6) & 7); \
        GLOAD_LDS16(&h[(size_t)(mb + _m) * DI + (K0) + _kg * 4], (float*)&Asl[BUF][_s]); \
    } \
    { \
        int _s = t; \
        int _o = _s >> 3; \
        int _kg = (_s & 7) ^ ((_s >> 5) & 7); \
        GLOAD_LDS16(&W[(size_t)(ob + _o) * DI + (K0) + _kg * 4], (float*)&Bsl[BUF][_s]); \
    } }

__global__ __launch_bounds__(512, 4)
void gemm_wh(const float* __restrict__ h, const float* __restrict__ W,
             float* __restrict__ Wh) {
    __shared__ __align__(16) float4 Asl[2][1024];  // 2 x 16 KB  [m(128)][kc(8)] swizzled
    __shared__ __align__(16) float4 Bsl[2][512];   // 2 x  8 KB  [o(64)][kc(8)] swizzled
    const int t  = threadIdx.x;
    const int mb = blockIdx.x * 128;
    const int ob = blockIdx.y * 64;
    const int rg = t >> 4;          // 0..31
    const int cg = t & 15;          // 0..15
    const int m0 = rg * 4, o0 = cg * 4;
    float acc[4][4] = {};

    GEMM_STAGE(0, 0);
    __syncthreads();                                  // prologue drain (once)
    for (int kb = 0; kb < 8; ++kb) {
        const int cur = kb & 1;
        if (kb < 7) GEMM_STAGE(cur ^ 1, (kb + 1) * 32);   // async under compute
        #pragma unroll
        for (int kg = 0; kg < 8; ++kg) {
            float4 bf[4], af[4];
            #pragma unroll
            for (int c = 0; c < 4; ++c) {
                int o = o0 + c;
                bf[c] = Bsl[cur][o * 8 + (kg ^ ((o >> 2) & 7))];
            }
            #pragma unroll
            for (int i = 0; i < 4; ++i) {
                int m = m0 + i;
                af[i] = Asl[cur][m * 8 + (kg ^ ((m >> 3) & 7))];
            }
            #pragma unroll
            for (int i = 0; i < 4; ++i)
                #pragma unroll
                for (int c = 0; c < 4; ++c) {
                    acc[i][c] += af[i].x * bf[c].x;
                    acc[i][c] += af[i].y * bf[c].y;
                    acc[i][c] += af[i].z * bf[c].z;
                    acc[i][c] += af[i].w * bf[c].w;
                }
        }
        __syncthreads();      // stage for kb+1 landed; reads of cur done
    }
    #pragma unroll
    for (int i = 0; i < 4; ++i)
        *(float4*)&Wh[(size_t)(mb + m0 + i) * DOv + ob + o0] =
            make_float4(acc[i][0], acc[i][1], acc[i][2], acc[i][3]);
}

// ---------------- Kernel 2: ei = Wh . a1 ; ej = Wh . a2 (per row) ----------------
__global__ __launch_bounds__(256)
void ei_ej(const float* __restrict__ Wh, const float* __restrict__ a,
           float* __restrict__ ei, float* __restrict__ ej) {
    const int t = threadIdx.x;
    const int w = t >> 6, l = t & 63;
    const int row = blockIdx.x * 4 + w;
    float4 wv = *(const float4*)&Wh[(size_t)row * DOv + l * 4];
    float4 a1 = *(const float4*)&a[l * 4];
    float4 a2 = *(const float4*)&a[DOv + l * 4];
    float s1 = wv.x*a1.x + wv.y*a1.y + wv.z*a1.z + wv.w*a1.w;
    float s2 = wv.x*a2.x + wv.y*a2.y + wv.z*a2.z + wv.w*a2.w;
    #pragma unroll
    for (int off = 32; off; off >>= 1) {
        s1 += __shfl_xor(s1, off);
        s2 += __shfl_xor(s2, off);
    }
    if (l == 0) { ei[row] = s1; ej[row] = s2; }
}

// ---------------- Kernel 3: fused masked-softmax attention + PV ----------------
// r3's proven structure (140 us measured: 2 barriers/tile, single ps) with
// whs double-buffered; STAGE(i+1) issued AFTER barrier#1, so the vmcnt(0)
// drain at barrier#2 sits under the full PV (~1500 cyc) instead of exposing
// HBM/L2 latency. NO lambdas, NO private arrays (scratch landmine of
// r4/r6/r7): named scalar accumulators + textual macros only.
// Softmax shift-invariance + |e|<=~8 -> no max pass; l==0 -> out 0 (ref NaN->0).
constexpr int RI = 32;   // rows per block
constexpr int TJ = 32;   // j-tile

#define ATTN_STAGE(BUF, TILE) { \
    const float* _src = whsrc + (size_t)(TILE) * TJ * DOv; \
    float* _dst = &whs[BUF][0]; \
    _Pragma("unroll") \
    for (int _r = 0; _r < 4; ++_r) { \
        int _idx = _r * 512 + t; \
        GLOAD_LDS16(_src + _idx * 4, _dst + _idx * 4); \
    } }

#define FMA4(K, PV, W) \
    acc##K##0 += (PV) * (W).x; acc##K##1 += (PV) * (W).y; \
    acc##K##2 += (PV) * (W).z; acc##K##3 += (PV) * (W).w;

#define PVSTEP(U, MEM) { \
    float4 w4 = *(const float4*)&whc[(j2 + U) * DOv + o0]; \
    FMA4(0, pk0.MEM, w4) FMA4(1, pk1.MEM, w4) \
    FMA4(2, pk2.MEM, w4) FMA4(3, pk3.MEM, w4) }

#define EPI(K) { \
    float lv = ls[m0 + K]; \
    float iv = lv > 0.f ? 1.0f / lv : 0.f; \
    *(float4*)&out[((size_t)b * NN + ib + m0 + K) * DOv + o0] = \
        make_float4(acc##K##0 * iv, acc##K##1 * iv, acc##K##2 * iv, acc##K##3 * iv); }

__global__ __launch_bounds__(512, 4)
void gat_attn(const float* __restrict__ Wh, const float* __restrict__ ei,
              const float* __restrict__ ej, const int* __restrict__ adj,
              float* __restrict__ out) {
    __shared__ __align__(16) float whs[2][TJ * DOv];   // 64 KB, LINEAR (gload_lds dest)
    __shared__ __align__(16) float ps[RI][TJ + 4];     // 4.6 KB
    __shared__ float ejs[NN];                          // 4 KB
    __shared__ float ls[RI];
    // ~74 KB -> 2 blocks/CU

    const int t = threadIdx.x;
    // XCD-bijective swizzle: 512 blocks = 8 XCDs * 64 -> 2 batches per XCD L2.
    const int swz = (blockIdx.x & 7) * 64 + (blockIdx.x >> 3);
    const int b  = swz >> 5;
    const int ib = (swz & 31) * RI;

    *(float2*)&ejs[t * 2] = *(const float2*)&ej[(size_t)b * NN + t * 2];

    const int erow = t >> 4;        // e-phase: 1 row x 2 j per thread
    const int ej0  = (t & 15) * 2;
    const int rg   = t >> 6;        // PV: wave 0..7
    const int m0   = rg * 4;        // wave-uniform -> ps reads broadcast
    const int o0   = (t & 63) * 4;  // ds_read_b128, conflict-free

    float acc00=0.f, acc01=0.f, acc02=0.f, acc03=0.f;
    float acc10=0.f, acc11=0.f, acc12=0.f, acc13=0.f;
    float acc20=0.f, acc21=0.f, acc22=0.f, acc23=0.f;
    float acc30=0.f, acc31=0.f, acc32=0.f, acc33=0.f;
    float lsum = 0.f;

    const float* whsrc = Wh + (size_t)b * NN * DOv;
    const int*   arow  = adj + ((size_t)b * NN + ib + erow) * NN;
    const float  eiv   = ei[(size_t)b * NN + ib + erow];

    ATTN_STAGE(0, 0);
    int2 amc = *(const int2*)&arow[ej0];
    __syncthreads();                    // whs[0] drained; ejs visible

    for (int i = 0; i < 32; ++i) {
        const int cur = i & 1;
        // ---- e-phase (plain code, writes single-buffered ps) ----
        float2 ejv = *(const float2*)&ejs[i * TJ + ej0];
        float e0 = eiv + ejv.x; e0 = e0 > 0.f ? e0 : NEG * e0;
        float e1 = eiv + ejv.y; e1 = e1 > 0.f ? e1 : NEG * e1;
        float p0 = amc.x ? __expf(e0) : 0.f;
        float p1 = amc.y ? __expf(e1) : 0.f;
        *(float2*)&ps[erow][ej0] = make_float2(p0, p1);
        lsum += p0 + p1;
        if (i + 1 < 32) amc = *(const int2*)&arow[(i + 1) * TJ + ej0];
        __syncthreads();                // barrier#1: ps visible (only amc load drained)
        if (i + 1 < 32) ATTN_STAGE(cur ^ 1, i + 1);   // async; whs[cur^1] free since PV(i-1)
        // ---- PV(i) on whs[cur] ----
        const float* whc = &whs[cur][0];
        #pragma unroll
        for (int j2 = 0; j2 < TJ; j2 += 4) {
            float4 pk0 = *(const float4*)&ps[m0 + 0][j2];
            float4 pk1 = *(const float4*)&ps[m0 + 1][j2];
            float4 pk2 = *(const float4*)&ps[m0 + 2][j2];
            float4 pk3 = *(const float4*)&ps[m0 + 3][j2];
            PVSTEP(0, x) PVSTEP(1, y) PVSTEP(2, z) PVSTEP(3, w)
        }
        __syncthreads();                // barrier#2: stage drained under PV; ps free
    }

    // reduce lsum over the 16 lanes sharing a row
    #pragma unroll
    for (int off = 8; off; off >>= 1) lsum += __shfl_xor(lsum, off);
    if ((t & 15) == 0) ls[erow] = lsum;
    __syncthreads();

    EPI(0) EPI(1) EPI(2) EPI(3)
}

// ---------------- launch ----------------
extern "C" void kernel_launch(void* const* d_in, const int* in_sizes, int n_in,
                              void* d_out, int out_size, void* d_ws, size_t ws_size,
                              hipStream_t stream) {
    const float* h   = (const float*)d_in[0];
    const int*   adj = (const int*)d_in[1];
    const float* W   = (const float*)d_in[2];
    const float* a   = (const float*)d_in[3];
    float* out = (float*)d_out;

    float* Wh = (float*)d_ws;                       // 16 MB
    float* ei = Wh + (size_t)NB * NN * DOv;
    float* ej = ei + (size_t)NB * NN;

    gemm_wh<<<dim3((NB * NN) / 128, DOv / 64), 512, 0, stream>>>(h, W, Wh);
    ei_ej<<<(NB * NN) / 4, 256, 0, stream>>>(Wh, a, ei, ej);
    gat_attn<<<NB * NN / RI, 512, 0, stream>>>(Wh, ei, ej, adj, out);
}

// Round 11
// 297.480 us; speedup vs baseline: 7.3015x; 1.0243x over previous
//
#include <hip/hip_runtime.h>
#include <hip/hip_bf16.h>

constexpr int NB = 16;      // batch
constexpr int NN = 1024;    // nodes
constexpr int DI = 256;     // in dim
constexpr int DOv = 256;    // out dim
constexpr float NEG = 0.2f;

#define GLOAD_LDS16(g, l) __builtin_amdgcn_global_load_lds( \
    (const __attribute__((address_space(1))) unsigned int*)(g), \
    (__attribute__((address_space(3))) unsigned int*)(l), 16, 0, 0)

// ---------------- Kernel 1: Wh[m][o] = sum_k h[m][k] * W[o][k] ----------------
// BM=128, BO=64, BK=32, 512 thr, 4x4 outputs/thread. Double-buffered
// global_load_lds staging, one barrier per K-step, STAGE(next) before compute.
// LDS linear (gload_lds requirement); conflicts broken by XOR-swizzling BOTH
// the per-lane global source and the read index (rule #21).
// __launch_bounds__(512, 2): 2nd arg is min BLOCKS/CU (CUDA semantics) ->
// (512,4) forced a 64-VGPR cap and silent scratch spill (r8: VGPR=64,
// 164 MB phantom WRITE). 2 blocks/CU -> 128-VGPR cap, matches LDS limit.
#define GEMM_STAGE(BUF, K0) { \
    _Pragma("unroll") \
    for (int _r = 0; _r < 2; ++_r) { \
        int _s = _r * 512 + t; \
        int _m = _s >> 3; \
        int _kg = (_s & 7) ^ ((_s >> 6) & 7); \
        GLOAD_LDS16(&h[(size_t)(mb + _m) * DI + (K0) + _kg * 4], (float*)&Asl[BUF][_s]); \
    } \
    { \
        int _s = t; \
        int _o = _s >> 3; \
        int _kg = (_s & 7) ^ ((_s >> 5) & 7); \
        GLOAD_LDS16(&W[(size_t)(ob + _o) * DI + (K0) + _kg * 4], (float*)&Bsl[BUF][_s]); \
    } }

__global__ __launch_bounds__(512, 2)
void gemm_wh(const float* __restrict__ h, const float* __restrict__ W,
             float* __restrict__ Wh) {
    __shared__ __align__(16) float4 Asl[2][1024];  // 2 x 16 KB  [m(128)][kc(8)] swizzled
    __shared__ __align__(16) float4 Bsl[2][512];   // 2 x  8 KB  [o(64)][kc(8)] swizzled
    const int t  = threadIdx.x;
    const int mb = blockIdx.x * 128;
    const int ob = blockIdx.y * 64;
    const int rg = t >> 4;          // 0..31
    const int cg = t & 15;          // 0..15
    const int m0 = rg * 4, o0 = cg * 4;
    float acc[4][4] = {};

    GEMM_STAGE(0, 0);
    __syncthreads();                                  // prologue drain (once)
    for (int kb = 0; kb < 8; ++kb) {
        const int cur = kb & 1;
        if (kb < 7) GEMM_STAGE(cur ^ 1, (kb + 1) * 32);   // async under compute
        #pragma unroll
        for (int kg = 0; kg < 8; ++kg) {
            float4 bf[4], af[4];
            #pragma unroll
            for (int c = 0; c < 4; ++c) {
                int o = o0 + c;
                bf[c] = Bsl[cur][o * 8 + (kg ^ ((o >> 2) & 7))];
            }
            #pragma unroll
            for (int i = 0; i < 4; ++i) {
                int m = m0 + i;
                af[i] = Asl[cur][m * 8 + (kg ^ ((m >> 3) & 7))];
            }
            #pragma unroll
            for (int i = 0; i < 4; ++i)
                #pragma unroll
                for (int c = 0; c < 4; ++c) {
                    acc[i][c] += af[i].x * bf[c].x;
                    acc[i][c] += af[i].y * bf[c].y;
                    acc[i][c] += af[i].z * bf[c].z;
                    acc[i][c] += af[i].w * bf[c].w;
                }
        }
        __syncthreads();      // stage for kb+1 landed; reads of cur done
    }
    #pragma unroll
    for (int i = 0; i < 4; ++i)
        *(float4*)&Wh[(size_t)(mb + m0 + i) * DOv + ob + o0] =
            make_float4(acc[i][0], acc[i][1], acc[i][2], acc[i][3]);
}

// ---------------- Kernel 2: ei = Wh . a1 ; ej = Wh . a2 (per row) ----------------
__global__ __launch_bounds__(256)
void ei_ej(const float* __restrict__ Wh, const float* __restrict__ a,
           float* __restrict__ ei, float* __restrict__ ej) {
    const int t = threadIdx.x;
    const int w = t >> 6, l = t & 63;
    const int row = blockIdx.x * 4 + w;
    float4 wv = *(const float4*)&Wh[(size_t)row * DOv + l * 4];
    float4 a1 = *(const float4*)&a[l * 4];
    float4 a2 = *(const float4*)&a[DOv + l * 4];
    float s1 = wv.x*a1.x + wv.y*a1.y + wv.z*a1.z + wv.w*a1.w;
    float s2 = wv.x*a2.x + wv.y*a2.y + wv.z*a2.z + wv.w*a2.w;
    #pragma unroll
    for (int off = 32; off; off >>= 1) {
        s1 += __shfl_xor(s1, off);
        s2 += __shfl_xor(s2, off);
    }
    if (l == 0) { ei[row] = s1; ej[row] = s2; }
}

// ---------------- Kernel 3: fused masked-softmax attention + PV ----------------
// r3's proven structure (2 barriers/tile, single ps) with whs double-buffered;
// STAGE(i+1) issued AFTER barrier#1 so the vmcnt(0) drain at barrier#2 sits
// under the full PV. NO lambdas, NO private arrays; named scalar accumulators
// + textual macros only. __launch_bounds__(512, 2): see gemm comment (the
// (512,4) 64-VGPR cap was this session's recurring spill disaster).
// Softmax shift-invariance + |e|<=~8 -> no max pass; l==0 -> out 0 (ref NaN->0).
constexpr int RI = 32;   // rows per block
constexpr int TJ = 32;   // j-tile

#define ATTN_STAGE(BUF, TILE) { \
    const float* _src = whsrc + (size_t)(TILE) * TJ * DOv; \
    float* _dst = &whs[BUF][0]; \
    _Pragma("unroll") \
    for (int _r = 0; _r < 4; ++_r) { \
        int _idx = _r * 512 + t; \
        GLOAD_LDS16(_src + _idx * 4, _dst + _idx * 4); \
    } }

#define FMA4(K, PV, W) \
    acc##K##0 += (PV) * (W).x; acc##K##1 += (PV) * (W).y; \
    acc##K##2 += (PV) * (W).z; acc##K##3 += (PV) * (W).w;

#define PVSTEP(U, MEM) { \
    float4 w4 = *(const float4*)&whc[(j2 + U) * DOv + o0]; \
    FMA4(0, pk0.MEM, w4) FMA4(1, pk1.MEM, w4) \
    FMA4(2, pk2.MEM, w4) FMA4(3, pk3.MEM, w4) }

#define EPI(K) { \
    float lv = ls[m0 + K]; \
    float iv = lv > 0.f ? 1.0f / lv : 0.f; \
    *(float4*)&out[((size_t)b * NN + ib + m0 + K) * DOv + o0] = \
        make_float4(acc##K##0 * iv, acc##K##1 * iv, acc##K##2 * iv, acc##K##3 * iv); }

__global__ __launch_bounds__(512, 2)
void gat_attn(const float* __restrict__ Wh, const float* __restrict__ ei,
              const float* __restrict__ ej, const int* __restrict__ adj,
              float* __restrict__ out) {
    __shared__ __align__(16) float whs[2][TJ * DOv];   // 64 KB, LINEAR (gload_lds dest)
    __shared__ __align__(16) float ps[RI][TJ + 4];     // 4.6 KB
    __shared__ float ejs[NN];                          // 4 KB
    __shared__ float ls[RI];
    // ~74 KB -> LDS caps residency at 2 blocks/CU (which lb now matches)

    const int t = threadIdx.x;
    // XCD-bijective swizzle: 512 blocks = 8 XCDs * 64 -> 2 batches per XCD L2.
    const int swz = (blockIdx.x & 7) * 64 + (blockIdx.x >> 3);
    const int b  = swz >> 5;
    const int ib = (swz & 31) * RI;

    *(float2*)&ejs[t * 2] = *(const float2*)&ej[(size_t)b * NN + t * 2];

    const int erow = t >> 4;        // e-phase: 1 row x 2 j per thread
    const int ej0  = (t & 15) * 2;
    const int rg   = t >> 6;        // PV: wave 0..7
    const int m0   = rg * 4;        // wave-uniform -> ps reads broadcast
    const int o0   = (t & 63) * 4;  // ds_read_b128, conflict-free

    float acc00=0.f, acc01=0.f, acc02=0.f, acc03=0.f;
    float acc10=0.f, acc11=0.f, acc12=0.f, acc13=0.f;
    float acc20=0.f, acc21=0.f, acc22=0.f, acc23=0.f;
    float acc30=0.f, acc31=0.f, acc32=0.f, acc33=0.f;
    float lsum = 0.f;

    const float* whsrc = Wh + (size_t)b * NN * DOv;
    const int*   arow  = adj + ((size_t)b * NN + ib + erow) * NN;
    const float  eiv   = ei[(size_t)b * NN + ib + erow];

    ATTN_STAGE(0, 0);
    int2 amc = *(const int2*)&arow[ej0];
    __syncthreads();                    // whs[0] drained; ejs visible

    for (int i = 0; i < 32; ++i) {
        const int cur = i & 1;
        // ---- e-phase (writes single-buffered ps) ----
        float2 ejv = *(const float2*)&ejs[i * TJ + ej0];
        float e0 = eiv + ejv.x; e0 = e0 > 0.f ? e0 : NEG * e0;
        float e1 = eiv + ejv.y; e1 = e1 > 0.f ? e1 : NEG * e1;
        float p0 = amc.x ? __expf(e0) : 0.f;
        float p1 = amc.y ? __expf(e1) : 0.f;
        *(float2*)&ps[erow][ej0] = make_float2(p0, p1);
        lsum += p0 + p1;
        if (i + 1 < 32) amc = *(const int2*)&arow[(i + 1) * TJ + ej0];
        __syncthreads();                // barrier#1: ps visible
        if (i + 1 < 32) ATTN_STAGE(cur ^ 1, i + 1);   // async; whs[cur^1] free since PV(i-1)
        // ---- PV(i) on whs[cur] ----
        const float* whc = &whs[cur][0];
        #pragma unroll
        for (int j2 = 0; j2 < TJ; j2 += 4) {
            float4 pk0 = *(const float4*)&ps[m0 + 0][j2];
            float4 pk1 = *(const float4*)&ps[m0 + 1][j2];
            float4 pk2 = *(const float4*)&ps[m0 + 2][j2];
            float4 pk3 = *(const float4*)&ps[m0 + 3][j2];
            PVSTEP(0, x) PVSTEP(1, y) PVSTEP(2, z) PVSTEP(3, w)
        }
        __syncthreads();                // barrier#2: stage drained under PV; ps free
    }

    // reduce lsum over the 16 lanes sharing a row
    #pragma unroll
    for (int off = 8; off; off >>= 1) lsum += __shfl_xor(lsum, off);
    if ((t & 15) == 0) ls[erow] = lsum;
    __syncthreads();

    EPI(0) EPI(1) EPI(2) EPI(3)
}

// ---------------- launch ----------------
extern "C" void kernel_launch(void* const* d_in, const int* in_sizes, int n_in,
                              void* d_out, int out_size, void* d_ws, size_t ws_size,
                              hipStream_t stream) {
    const float* h   = (const float*)d_in[0];
    const int*   adj = (const int*)d_in[1];
    const float* W   = (const float*)d_in[2];
    const float* a   = (const float*)d_in[3];
    float* out = (float*)d_out;

    float* Wh = (float*)d_ws;                       // 16 MB
    float* ei = Wh + (size_t)NB * NN * DOv;
    float* ej = ei + (size_t)NB * NN;

    gemm_wh<<<dim3((NB * NN) / 128, DOv / 64), 512, 0, stream>>>(h, W, Wh);
    ei_ej<<<(NB * NN) / 4, 256, 0, stream>>>(Wh, a, ei, ej);
    gat_attn<<<NB * NN / RI, 512, 0, stream>>>(Wh, ei, ej, adj, out);
}